// Round 1
// baseline (87.322 us; speedup 1.0000x reference)
//
#include <hip/hip_runtime.h>

// Problem constants (K=32, T=16, n=4, L=4 → quadratic-relaxation branch)
static constexpr int       KT    = 512;         // K*T
static constexpr int       TROWS = 1025;        // 2*K*T + 1 rows in under/over
static constexpr long long PAIRS = 1050625LL;   // TROWS^2
static constexpr long long ROWSO = 1051651LL;   // PAIRS + TROWS + 1
static constexpr long long RUF   = ROWSO * 28;  // floats per output tensor = 29446228

// workspace layout (floats)
static constexpr int WS_UNDER = 0;
static constexpr int WS_OVER  = TROWS * 16;      // 16400
static constexpr int WS_SCAL  = 2 * TROWS * 16;  // 32800 : cu[3], co[3]

__device__ __forceinline__ void row_interval(const float q[16], float& Lr, float& Ur)
{
    float L_ = fminf(fminf(q[0], q[1]), fminf(q[2], q[3]));
    float U_ = fmaxf(fmaxf(q[0], q[1]), fmaxf(q[2], q[3]));
#pragma unroll
    for (int v = 1; v < 4; ++v) {
        const float a0 = q[4*v+0], a1 = q[4*v+1], a2 = q[4*v+2], a3 = q[4*v+3];
        const float lo = fminf(fminf(a0, a1), fminf(a2, a3));
        const float hi = fmaxf(fmaxf(a0, a1), fmaxf(a2, a3));
        const float c0 = L_*lo, c1 = L_*hi, c2 = U_*lo, c3 = U_*hi;
        L_ = fminf(fminf(c0, c1), fminf(c2, c3));
        U_ = fmaxf(fmaxf(c0, c1), fmaxf(c2, c3));
    }
    Lr = L_; Ur = U_;
}

// Phase A: build under/over rows, interval bounds l,u, relaxation coefficients.
__global__ __launch_bounds__(1024)
void phaseA(const float* __restrict__ iu, const float* __restrict__ io,
            const float* __restrict__ posw, const float* __restrict__ negw,
            const float* __restrict__ biasp, float* __restrict__ ws)
{
    __shared__ float sl[1024];
    __shared__ float su[1024];
    const int t = threadIdx.x;            // row 0..1023 (row 1024 handled by t==0)
    const float bias = biasp[0];

    const float* src = (t < KT) ? io : iu;
    const int s  = (t < KT) ? t : t - KT;
    const int k  = s >> 4;
    const int tt = s & 15;
    const float* row = src + k * 256 + tt * 16;

    float p[16];
#pragma unroll
    for (int i = 0; i < 16; ++i) p[i] = row[i];

    const float wU = (t < KT) ? negw[k] : posw[k];  // under: [io*neg ; iu*pos]
    const float wO = (t < KT) ? posw[k] : negw[k];  // over : [io*pos ; iu*neg]

    float un[16], ov[16];
#pragma unroll
    for (int i = 0; i < 16; ++i) {
        const float sU = (i < 4) ? wU : 1.0f;   // weight applies to variable 0 only
        const float sO = (i < 4) ? wO : 1.0f;
        un[i] = p[i] * sU;
        ov[i] = p[i] * sO;
    }
#pragma unroll
    for (int i = 0; i < 16; ++i) {
        ws[WS_UNDER + t * 16 + i] = un[i];
        ws[WS_OVER  + t * 16 + i] = ov[i];
    }

    float Lu, Uu, Lo, Uo;
    row_interval(un, Lu, Uu);
    row_interval(ov, Lo, Uo);
    sl[t] = Lu;   // lower bound contribution (under)
    su[t] = Uo;   // upper bound contribution (over)
    __syncthreads();
    for (int off = 512; off > 0; off >>= 1) {
        if (t < off) { sl[t] += sl[t + off]; su[t] += su[t + off]; }
        __syncthreads();
    }
    if (t == 0) {
        // const row (index 1024): var0 = bias everywhere, others = 1
#pragma unroll
        for (int i = 0; i < 16; ++i) {
            const float cv = (i < 4) ? bias : 1.0f;
            ws[WS_UNDER + 1024 * 16 + i] = cv;
            ws[WS_OVER  + 1024 * 16 + i] = cv;
        }
        const float l = sl[0] + bias;   // const row contributes [bias,bias]
        const float u = su[0] + bias;
        const float d    = u - l;
        const float inv  = 1.0f / d;
        const float inv2 = inv * inv;
        ws[WS_SCAL + 0] = inv;                 // cu.a
        ws[WS_SCAL + 1] = -l * inv;            // cu.b
        ws[WS_SCAL + 2] = 0.0f;                // cu.c
        ws[WS_SCAL + 3] = u * inv2;            // co.a
        ws[WS_SCAL + 4] = -2.0f * u * l * inv2;// co.b
        ws[WS_SCAL + 5] = u * l * l * inv2;    // co.c
    }
}

// Phase B: the pairwise Bernstein square (all 1025^2 pairs, both tensors).
// Each thread -> one (a,b) pair -> 28 contiguous floats (7x float4 stores).
__global__ __launch_bounds__(256)
void phaseB(const float* __restrict__ ws, float* __restrict__ out)
{
    const long long idx = (long long)blockIdx.x * 256 + threadIdx.x;
    if (idx >= PAIRS) return;
    const int sel = blockIdx.y;                // 0 = ru/under/cu, 1 = ro/over/co
    const unsigned r = (unsigned)idx;
    const unsigned a = r / 1025u;
    const unsigned b = r - a * 1025u;

    const float* P  = ws + sel * WS_OVER;
    const float  A  = ws[WS_SCAL + sel * 3];
    const float* pa = P + a * 16;
    const float* pb = P + b * 16;

    float o[28];
#pragma unroll
    for (int v = 0; v < 4; ++v) {
        const float wa0 = pa[4*v+0],       wa1 = pa[4*v+1] * 3.f;
        const float wa2 = pa[4*v+2] * 3.f, wa3 = pa[4*v+3];
        const float wb0 = pb[4*v+0],       wb1 = pb[4*v+1] * 3.f;
        const float wb2 = pb[4*v+2] * 3.f, wb3 = pb[4*v+3];
        const float sA = (v == 0) ? A : 1.0f;
        o[7*v+0] = (wa0*wb0) * sA;
        o[7*v+1] = (wa0*wb1 + wa1*wb0) * (sA * (1.f/6.f));
        o[7*v+2] = (wa0*wb2 + wa1*wb1 + wa2*wb0) * (sA * (1.f/15.f));
        o[7*v+3] = (wa0*wb3 + wa1*wb2 + wa2*wb1 + wa3*wb0) * (sA * 0.05f);
        o[7*v+4] = (wa1*wb3 + wa2*wb2 + wa3*wb1) * (sA * (1.f/15.f));
        o[7*v+5] = (wa2*wb3 + wa3*wb2) * (sA * (1.f/6.f));
        o[7*v+6] = (wa3*wb3) * sA;
    }

    float4*       dst = (float4*)(out + (long long)sel * RUF + (long long)r * 28);
    const float4* s4  = (const float4*)o;
#pragma unroll
    for (int q = 0; q < 7; ++q) dst[q] = s4[q];
}

// Phase C: degree-elevation rows (bp), const-term rows, and the 2*deg outputs.
__global__ __launch_bounds__(256)
void phaseC(const float* __restrict__ ws,
            const int* __restrict__ degu, const int* __restrict__ dego,
            float* __restrict__ out)
{
    const int id = blockIdx.x * 256 + threadIdx.x;
    if (id < 2 * (TROWS + 1)) {
        const int sel = id / (TROWS + 1);
        const int t   = id - sel * (TROWS + 1);
        const float B = ws[WS_SCAL + sel * 3 + 1];
        const float C = ws[WS_SCAL + sel * 3 + 2];
        float o[28];
        if (t < TROWS) {
            const float* P = ws + sel * WS_OVER + t * 16;
#pragma unroll
            for (int v = 0; v < 4; ++v) {
                const float sB = (v == 0) ? B : 1.0f;
                const float q0 = P[4*v+0]*sB, q1 = P[4*v+1]*sB;
                const float q2 = P[4*v+2]*sB, q3 = P[4*v+3]*sB;
                // Bernstein degree elevation 3 -> 6
                o[7*v+0] = q0;
                o[7*v+1] = 0.5f*(q0 + q1);
                o[7*v+2] = 0.2f*q0 + 0.6f*q1 + 0.2f*q2;
                o[7*v+3] = 0.05f*q0 + 0.45f*q1 + 0.45f*q2 + 0.05f*q3;
                o[7*v+4] = 0.2f*q1 + 0.6f*q2 + 0.2f*q3;
                o[7*v+5] = 0.5f*(q2 + q3);
                o[7*v+6] = q3;
            }
        } else {
            // const-term row: var0 = C everywhere, others = 1
#pragma unroll
            for (int j = 0; j < 28; ++j) o[j] = (j < 7) ? C : 1.0f;
        }
        float* dst = out + (long long)sel * RUF + (PAIRS + (long long)t) * 28LL;
#pragma unroll
        for (int j = 0; j < 28; ++j) dst[j] = o[j];
    } else if (id < 2 * (TROWS + 1) + 8) {
        const int j = id - 2 * (TROWS + 1);
        const int v = j & 3;
        int m = 0;
        for (int k = 0; k < 32; ++k)
            m = max(m, max(degu[k * 4 + v], dego[k * 4 + v]));
        out[2 * RUF + j] = 2.0f * (float)m;   // out[2] (j<4) and out[3] (j>=4)
    }
}

extern "C" void kernel_launch(void* const* d_in, const int* in_sizes, int n_in,
                              void* d_out, int out_size, void* d_ws, size_t ws_size,
                              hipStream_t stream)
{
    const float* iu   = (const float*)d_in[0];
    const float* io   = (const float*)d_in[1];
    const int*   degu = (const int*)d_in[2];
    const int*   dego = (const int*)d_in[3];
    const float* posw = (const float*)d_in[4];
    const float* negw = (const float*)d_in[5];
    const float* bias = (const float*)d_in[6];
    float* out = (float*)d_out;
    float* ws  = (float*)d_ws;

    hipLaunchKernelGGL(phaseA, dim3(1), dim3(1024), 0, stream,
                       iu, io, posw, negw, bias, ws);

    const int nb = (int)((PAIRS + 255) / 256);   // 4105 blocks per tensor
    hipLaunchKernelGGL(phaseB, dim3(nb, 2), dim3(256), 0, stream, ws, out);

    hipLaunchKernelGGL(phaseC, dim3(9), dim3(256), 0, stream,
                       ws, degu, dego, out);
}

// Round 2
// 51.578 us; speedup vs baseline: 1.6930x; 1.6930x over previous
//
#include <hip/hip_runtime.h>

// Problem constants (K=32, T=16, n=4, L=4 → quadratic-relaxation branch)
static constexpr int       KT    = 512;         // K*T
static constexpr int       TROWS = 1025;        // 2*K*T + 1 rows in under/over
static constexpr long long PAIRS = 1050625LL;   // TROWS^2
static constexpr long long ROWSO = 1051651LL;   // PAIRS + TROWS + 1
static constexpr long long RUF   = ROWSO * 28;  // floats per output tensor

// workspace layout (floats)
static constexpr int WS_UNDER = 0;
static constexpr int WS_OVER  = TROWS * 16;      // 16400
static constexpr int WS_SCAL  = 2 * TROWS * 16;  // 32800 : cu[3], co[3]

__device__ __forceinline__ void row_interval(const float q[16], float& Lr, float& Ur)
{
    float L_ = fminf(fminf(q[0], q[1]), fminf(q[2], q[3]));
    float U_ = fmaxf(fmaxf(q[0], q[1]), fmaxf(q[2], q[3]));
#pragma unroll
    for (int v = 1; v < 4; ++v) {
        const float a0 = q[4*v+0], a1 = q[4*v+1], a2 = q[4*v+2], a3 = q[4*v+3];
        const float lo = fminf(fminf(a0, a1), fminf(a2, a3));
        const float hi = fmaxf(fmaxf(a0, a1), fmaxf(a2, a3));
        const float c0 = L_*lo, c1 = L_*hi, c2 = U_*lo, c3 = U_*hi;
        L_ = fminf(fminf(c0, c1), fminf(c2, c3));
        U_ = fmaxf(fmaxf(c0, c1), fmaxf(c2, c3));
    }
    Lr = L_; Ur = U_;
}

// Phase A: build under/over rows, interval bounds l,u, relaxation coefficients.
__global__ __launch_bounds__(1024)
void phaseA(const float* __restrict__ iu, const float* __restrict__ io,
            const float* __restrict__ posw, const float* __restrict__ negw,
            const float* __restrict__ biasp, float* __restrict__ ws)
{
    __shared__ float sl[1024];
    __shared__ float su[1024];
    const int t = threadIdx.x;            // row 0..1023 (row 1024 handled by t==0)
    const float bias = biasp[0];

    const float* src = (t < KT) ? io : iu;
    const int s  = (t < KT) ? t : t - KT;
    const int k  = s >> 4;
    const int tt = s & 15;
    const float* row = src + k * 256 + tt * 16;

    float p[16];
#pragma unroll
    for (int i = 0; i < 16; ++i) p[i] = row[i];

    const float wU = (t < KT) ? negw[k] : posw[k];  // under: [io*neg ; iu*pos]
    const float wO = (t < KT) ? posw[k] : negw[k];  // over : [io*pos ; iu*neg]

    float un[16], ov[16];
#pragma unroll
    for (int i = 0; i < 16; ++i) {
        const float sU = (i < 4) ? wU : 1.0f;   // weight applies to variable 0 only
        const float sO = (i < 4) ? wO : 1.0f;
        un[i] = p[i] * sU;
        ov[i] = p[i] * sO;
    }
#pragma unroll
    for (int i = 0; i < 16; ++i) {
        ws[WS_UNDER + t * 16 + i] = un[i];
        ws[WS_OVER  + t * 16 + i] = ov[i];
    }

    float Lu, Uu, Lo, Uo;
    row_interval(un, Lu, Uu);
    row_interval(ov, Lo, Uo);
    sl[t] = Lu;   // lower bound contribution (under)
    su[t] = Uo;   // upper bound contribution (over)
    __syncthreads();
    for (int off = 512; off > 0; off >>= 1) {
        if (t < off) { sl[t] += sl[t + off]; su[t] += su[t + off]; }
        __syncthreads();
    }
    if (t == 0) {
        // const row (index 1024): var0 = bias everywhere, others = 1
#pragma unroll
        for (int i = 0; i < 16; ++i) {
            const float cv = (i < 4) ? bias : 1.0f;
            ws[WS_UNDER + 1024 * 16 + i] = cv;
            ws[WS_OVER  + 1024 * 16 + i] = cv;
        }
        const float l = sl[0] + bias;   // const row contributes [bias,bias]
        const float u = su[0] + bias;
        const float d    = u - l;
        const float inv  = 1.0f / d;
        const float inv2 = inv * inv;
        ws[WS_SCAL + 0] = inv;                 // cu.a
        ws[WS_SCAL + 1] = -l * inv;            // cu.b
        ws[WS_SCAL + 2] = 0.0f;                // cu.c
        ws[WS_SCAL + 3] = u * inv2;            // co.a
        ws[WS_SCAL + 4] = -2.0f * u * l * inv2;// co.b
        ws[WS_SCAL + 5] = u * l * l * inv2;    // co.c
    }
}

// Phase B: pairwise Bernstein square. Compute 28 floats/pair into LDS
// (stride 29 to dodge bank conflicts), then write out fully coalesced:
// each store instruction = 64 lanes x 16B contiguous = 16 full 64B lines.
__global__ __launch_bounds__(256)
void phaseB(const float* __restrict__ ws, float* __restrict__ out)
{
    __shared__ float lds[256 * 29];          // 29,696 B
    const int t = threadIdx.x;
    const long long blockPair = (long long)blockIdx.x * 256;
    const long long idx = blockPair + t;
    const int sel = blockIdx.y;              // 0 = ru/under/cu, 1 = ro/over/co

    const float* P = ws + sel * WS_OVER;
    const float  A = ws[WS_SCAL + sel * 3];

    if (idx < PAIRS) {
        const unsigned r = (unsigned)idx;
        const unsigned a = r / 1025u;
        const unsigned b = r - a * 1025u;
        const float* pa = P + a * 16;
        const float* pb = P + b * 16;

        float o[28];
#pragma unroll
        for (int v = 0; v < 4; ++v) {
            const float wa0 = pa[4*v+0],       wa1 = pa[4*v+1] * 3.f;
            const float wa2 = pa[4*v+2] * 3.f, wa3 = pa[4*v+3];
            const float wb0 = pb[4*v+0],       wb1 = pb[4*v+1] * 3.f;
            const float wb2 = pb[4*v+2] * 3.f, wb3 = pb[4*v+3];
            const float sA = (v == 0) ? A : 1.0f;
            o[7*v+0] = (wa0*wb0) * sA;
            o[7*v+1] = (wa0*wb1 + wa1*wb0) * (sA * (1.f/6.f));
            o[7*v+2] = (wa0*wb2 + wa1*wb1 + wa2*wb0) * (sA * (1.f/15.f));
            o[7*v+3] = (wa0*wb3 + wa1*wb2 + wa2*wb1 + wa3*wb0) * (sA * 0.05f);
            o[7*v+4] = (wa1*wb3 + wa2*wb2 + wa3*wb1) * (sA * (1.f/15.f));
            o[7*v+5] = (wa2*wb3 + wa3*wb2) * (sA * (1.f/6.f));
            o[7*v+6] = (wa3*wb3) * sA;
        }
#pragma unroll
        for (int j = 0; j < 28; ++j) lds[t * 29 + j] = o[j];
    }
    __syncthreads();

    // Coalesced drain: 1792 float4-chunks per block, 7 per thread.
    const long long totalChunks = PAIRS * 7;
    float* outT = out + (long long)sel * RUF;
#pragma unroll
    for (int it = 0; it < 7; ++it) {
        const int local = it * 256 + t;          // 0..1791 chunk within block
        const long long c = blockPair * 7 + local;
        if (c < totalChunks) {
            const int p = local / 7;             // pair within block (magic-mul)
            const int q = local - p * 7;         // float4 index within pair
            float4 vv;
            vv.x = lds[p * 29 + q * 4 + 0];
            vv.y = lds[p * 29 + q * 4 + 1];
            vv.z = lds[p * 29 + q * 4 + 2];
            vv.w = lds[p * 29 + q * 4 + 3];
            ((float4*)outT)[c] = vv;
        }
    }
}

// Phase C: degree-elevation rows (bp), const-term rows, and the 2*deg outputs.
__global__ __launch_bounds__(256)
void phaseC(const float* __restrict__ ws,
            const int* __restrict__ degu, const int* __restrict__ dego,
            float* __restrict__ out)
{
    const int id = blockIdx.x * 256 + threadIdx.x;
    if (id < 2 * (TROWS + 1)) {
        const int sel = id / (TROWS + 1);
        const int t   = id - sel * (TROWS + 1);
        const float B = ws[WS_SCAL + sel * 3 + 1];
        const float C = ws[WS_SCAL + sel * 3 + 2];
        float o[28];
        if (t < TROWS) {
            const float* P = ws + sel * WS_OVER + t * 16;
#pragma unroll
            for (int v = 0; v < 4; ++v) {
                const float sB = (v == 0) ? B : 1.0f;
                const float q0 = P[4*v+0]*sB, q1 = P[4*v+1]*sB;
                const float q2 = P[4*v+2]*sB, q3 = P[4*v+3]*sB;
                // Bernstein degree elevation 3 -> 6
                o[7*v+0] = q0;
                o[7*v+1] = 0.5f*(q0 + q1);
                o[7*v+2] = 0.2f*q0 + 0.6f*q1 + 0.2f*q2;
                o[7*v+3] = 0.05f*q0 + 0.45f*q1 + 0.45f*q2 + 0.05f*q3;
                o[7*v+4] = 0.2f*q1 + 0.6f*q2 + 0.2f*q3;
                o[7*v+5] = 0.5f*(q2 + q3);
                o[7*v+6] = q3;
            }
        } else {
            // const-term row: var0 = C everywhere, others = 1
#pragma unroll
            for (int j = 0; j < 28; ++j) o[j] = (j < 7) ? C : 1.0f;
        }
        float* dst = out + (long long)sel * RUF + (PAIRS + (long long)t) * 28LL;
#pragma unroll
        for (int j = 0; j < 28; ++j) dst[j] = o[j];
    } else if (id < 2 * (TROWS + 1) + 8) {
        const int j = id - 2 * (TROWS + 1);
        const int v = j & 3;
        int m = 0;
        for (int k = 0; k < 32; ++k)
            m = max(m, max(degu[k * 4 + v], dego[k * 4 + v]));
        out[2 * RUF + j] = 2.0f * (float)m;   // out[2] (j<4) and out[3] (j>=4)
    }
}

extern "C" void kernel_launch(void* const* d_in, const int* in_sizes, int n_in,
                              void* d_out, int out_size, void* d_ws, size_t ws_size,
                              hipStream_t stream)
{
    const float* iu   = (const float*)d_in[0];
    const float* io   = (const float*)d_in[1];
    const int*   degu = (const int*)d_in[2];
    const int*   dego = (const int*)d_in[3];
    const float* posw = (const float*)d_in[4];
    const float* negw = (const float*)d_in[5];
    const float* bias = (const float*)d_in[6];
    float* out = (float*)d_out;
    float* ws  = (float*)d_ws;

    hipLaunchKernelGGL(phaseA, dim3(1), dim3(1024), 0, stream,
                       iu, io, posw, negw, bias, ws);

    const int nb = (int)((PAIRS + 255) / 256);   // 4105 blocks per tensor
    hipLaunchKernelGGL(phaseB, dim3(nb, 2), dim3(256), 0, stream, ws, out);

    hipLaunchKernelGGL(phaseC, dim3(9), dim3(256), 0, stream,
                       ws, degu, dego, out);
}

// Round 3
// 48.119 us; speedup vs baseline: 1.8147x; 1.0719x over previous
//
#include <hip/hip_runtime.h>

// Problem constants (K=32, T=16, n=4, L=4 → quadratic-relaxation branch)
static constexpr int       KT    = 512;         // K*T
static constexpr int       TROWS = 1025;        // 2*K*T + 1 rows in under/over
static constexpr long long PAIRS = 1050625LL;   // TROWS^2
static constexpr long long ROWSO = 1051651LL;   // PAIRS + TROWS + 1
static constexpr long long RUF   = ROWSO * 28;  // floats per output tensor
static constexpr int       NB    = 4105;        // ceil(PAIRS/256) pair-blocks per sel
static constexpr int       NTAIL = 5;           // ceil(1026/256) tail blocks per sel

// workspace layout (floats)
static constexpr int WS_UNDER = 0;
static constexpr int WS_OVER  = TROWS * 16;      // 16400
static constexpr int WS_SCAL  = 2 * TROWS * 16;  // 32800 : cu[3], co[3]

__device__ __forceinline__ void row_interval(const float q[16], float& Lr, float& Ur)
{
    float L_ = fminf(fminf(q[0], q[1]), fminf(q[2], q[3]));
    float U_ = fmaxf(fmaxf(q[0], q[1]), fmaxf(q[2], q[3]));
#pragma unroll
    for (int v = 1; v < 4; ++v) {
        const float a0 = q[4*v+0], a1 = q[4*v+1], a2 = q[4*v+2], a3 = q[4*v+3];
        const float lo = fminf(fminf(a0, a1), fminf(a2, a3));
        const float hi = fmaxf(fmaxf(a0, a1), fmaxf(a2, a3));
        const float c0 = L_*lo, c1 = L_*hi, c2 = U_*lo, c3 = U_*hi;
        L_ = fminf(fminf(c0, c1), fminf(c2, c3));
        U_ = fmaxf(fmaxf(c0, c1), fmaxf(c2, c3));
    }
    Lr = L_; Ur = U_;
}

// Phase A: build under/over rows, interval bounds l,u, relaxation coefficients.
// Single block, 1024 threads; one barrier (wave-shuffle reduction).
__global__ __launch_bounds__(1024)
void phaseA(const float* __restrict__ iu, const float* __restrict__ io,
            const float* __restrict__ posw, const float* __restrict__ negw,
            const float* __restrict__ biasp, float* __restrict__ ws)
{
    __shared__ float sl[16];
    __shared__ float su[16];
    const int t = threadIdx.x;            // row 0..1023 (row 1024 handled by t==0)
    const float bias = biasp[0];

    const float* src = (t < KT) ? io : iu;
    const int s  = (t < KT) ? t : t - KT;
    const int k  = s >> 4;

    const float4* rp = (const float4*)(src + s * 16);
    const float4 r0 = rp[0], r1 = rp[1], r2 = rp[2], r3 = rp[3];
    const float p[16] = { r0.x, r0.y, r0.z, r0.w, r1.x, r1.y, r1.z, r1.w,
                          r2.x, r2.y, r2.z, r2.w, r3.x, r3.y, r3.z, r3.w };

    const float wU = (t < KT) ? negw[k] : posw[k];  // under: [io*neg ; iu*pos]
    const float wO = (t < KT) ? posw[k] : negw[k];  // over : [io*pos ; iu*neg]

    float un[16], ov[16];
#pragma unroll
    for (int i = 0; i < 16; ++i) {
        const float sU = (i < 4) ? wU : 1.0f;   // weight applies to variable 0 only
        const float sO = (i < 4) ? wO : 1.0f;
        un[i] = p[i] * sU;
        ov[i] = p[i] * sO;
    }
    float4* wu4 = (float4*)(ws + WS_UNDER + t * 16);
    float4* wo4 = (float4*)(ws + WS_OVER  + t * 16);
#pragma unroll
    for (int i = 0; i < 4; ++i) {
        wu4[i] = make_float4(un[4*i], un[4*i+1], un[4*i+2], un[4*i+3]);
        wo4[i] = make_float4(ov[4*i], ov[4*i+1], ov[4*i+2], ov[4*i+3]);
    }

    float Lu, Uu, Lo, Uo;
    row_interval(un, Lu, Uu);
    row_interval(ov, Lo, Uo);
    float accL = Lu;   // lower bound contribution (under)
    float accU = Uo;   // upper bound contribution (over)
#pragma unroll
    for (int off = 32; off > 0; off >>= 1) {
        accL += __shfl_down(accL, off, 64);
        accU += __shfl_down(accU, off, 64);
    }
    if ((t & 63) == 0) { sl[t >> 6] = accL; su[t >> 6] = accU; }
    __syncthreads();
    if (t == 0) {
        // const row (index 1024): var0 = bias everywhere, others = 1
#pragma unroll
        for (int i = 0; i < 16; ++i) {
            const float cv = (i < 4) ? bias : 1.0f;
            ws[WS_UNDER + 1024 * 16 + i] = cv;
            ws[WS_OVER  + 1024 * 16 + i] = cv;
        }
        float l = bias, u = bias;   // const row contributes [bias,bias]
#pragma unroll
        for (int w = 0; w < 16; ++w) { l += sl[w]; u += su[w]; }
        const float d    = u - l;
        const float inv  = 1.0f / d;
        const float inv2 = inv * inv;
        ws[WS_SCAL + 0] = inv;                 // cu.a
        ws[WS_SCAL + 1] = -l * inv;            // cu.b
        ws[WS_SCAL + 2] = 0.0f;                // cu.c
        ws[WS_SCAL + 3] = u * inv2;            // co.a
        ws[WS_SCAL + 4] = -2.0f * u * l * inv2;// co.b
        ws[WS_SCAL + 5] = u * l * l * inv2;    // co.c
    }
}

// Phase B+C fused. Pair-blocks (bx < NB): Bernstein square via LDS staging +
// fully coalesced drain. Tail-blocks (bx >= NB): degree-elevation rows,
// const-term rows, and the 2*deg outputs.
__global__ __launch_bounds__(256)
void phaseBC(const float* __restrict__ ws,
             const int* __restrict__ degu, const int* __restrict__ dego,
             float* __restrict__ out)
{
    __shared__ float lds[256 * 29];          // 29,696 B
    const int t   = threadIdx.x;
    const int bx  = blockIdx.x;
    const int sel = blockIdx.y;              // 0 = ru/under/cu, 1 = ro/over/co
    float* outT = out + (long long)sel * RUF;

    if (bx >= NB) {
        // ---- tail: elevation rows + const row + deg outputs ----
        const int id2 = (bx - NB) * 256 + t;
        const float B = ws[WS_SCAL + sel * 3 + 1];
        const float C = ws[WS_SCAL + sel * 3 + 2];
        if (id2 <= TROWS) {
            float o[28];
            if (id2 < TROWS) {
                const float* P = ws + sel * WS_OVER + id2 * 16;
#pragma unroll
                for (int v = 0; v < 4; ++v) {
                    const float sB = (v == 0) ? B : 1.0f;
                    const float q0 = P[4*v+0]*sB, q1 = P[4*v+1]*sB;
                    const float q2 = P[4*v+2]*sB, q3 = P[4*v+3]*sB;
                    // Bernstein degree elevation 3 -> 6
                    o[7*v+0] = q0;
                    o[7*v+1] = 0.5f*(q0 + q1);
                    o[7*v+2] = 0.2f*q0 + 0.6f*q1 + 0.2f*q2;
                    o[7*v+3] = 0.05f*q0 + 0.45f*q1 + 0.45f*q2 + 0.05f*q3;
                    o[7*v+4] = 0.2f*q1 + 0.6f*q2 + 0.2f*q3;
                    o[7*v+5] = 0.5f*(q2 + q3);
                    o[7*v+6] = q3;
                }
            } else {
                // const-term row: var0 = C everywhere, others = 1
#pragma unroll
                for (int j = 0; j < 28; ++j) o[j] = (j < 7) ? C : 1.0f;
            }
            float* dst = outT + (PAIRS + (long long)id2) * 28LL;
#pragma unroll
            for (int j = 0; j < 28; ++j) dst[j] = o[j];
        } else if (sel == 0 && id2 >= TROWS + 1 && id2 < TROWS + 9) {
            const int j = id2 - (TROWS + 1);
            const int v = j & 3;
            int m = 0;
            for (int kk = 0; kk < 32; ++kk)
                m = max(m, max(degu[kk * 4 + v], dego[kk * 4 + v]));
            out[2 * RUF + j] = 2.0f * (float)m;   // out[2] (j<4) and out[3] (j>=4)
        }
        return;
    }

    // ---- pair blocks: Bernstein square ----
    const long long blockPair = (long long)bx * 256;
    const long long idx = blockPair + t;

    const float* P = ws + sel * WS_OVER;
    const float  A = ws[WS_SCAL + sel * 3];

    if (idx < PAIRS) {
        const unsigned r = (unsigned)idx;
        const unsigned a = r / 1025u;
        const unsigned b = r - a * 1025u;
        const float* pa = P + a * 16;
        const float* pb = P + b * 16;

        float o[28];
#pragma unroll
        for (int v = 0; v < 4; ++v) {
            const float wa0 = pa[4*v+0],       wa1 = pa[4*v+1] * 3.f;
            const float wa2 = pa[4*v+2] * 3.f, wa3 = pa[4*v+3];
            const float wb0 = pb[4*v+0],       wb1 = pb[4*v+1] * 3.f;
            const float wb2 = pb[4*v+2] * 3.f, wb3 = pb[4*v+3];
            const float sA = (v == 0) ? A : 1.0f;
            o[7*v+0] = (wa0*wb0) * sA;
            o[7*v+1] = (wa0*wb1 + wa1*wb0) * (sA * (1.f/6.f));
            o[7*v+2] = (wa0*wb2 + wa1*wb1 + wa2*wb0) * (sA * (1.f/15.f));
            o[7*v+3] = (wa0*wb3 + wa1*wb2 + wa2*wb1 + wa3*wb0) * (sA * 0.05f);
            o[7*v+4] = (wa1*wb3 + wa2*wb2 + wa3*wb1) * (sA * (1.f/15.f));
            o[7*v+5] = (wa2*wb3 + wa3*wb2) * (sA * (1.f/6.f));
            o[7*v+6] = (wa3*wb3) * sA;
        }
#pragma unroll
        for (int j = 0; j < 28; ++j) lds[t * 29 + j] = o[j];
    }
    __syncthreads();

    // Coalesced drain: 1792 float4-chunks per block, 7 per thread.
    const long long totalChunks = PAIRS * 7;
#pragma unroll
    for (int it = 0; it < 7; ++it) {
        const int local = it * 256 + t;          // 0..1791 chunk within block
        const long long c = blockPair * 7 + local;
        if (c < totalChunks) {
            const int p = local / 7;             // pair within block (magic-mul)
            const int q = local - p * 7;         // float4 index within pair
            float4 vv;
            vv.x = lds[p * 29 + q * 4 + 0];
            vv.y = lds[p * 29 + q * 4 + 1];
            vv.z = lds[p * 29 + q * 4 + 2];
            vv.w = lds[p * 29 + q * 4 + 3];
            ((float4*)outT)[c] = vv;
        }
    }
}

extern "C" void kernel_launch(void* const* d_in, const int* in_sizes, int n_in,
                              void* d_out, int out_size, void* d_ws, size_t ws_size,
                              hipStream_t stream)
{
    const float* iu   = (const float*)d_in[0];
    const float* io   = (const float*)d_in[1];
    const int*   degu = (const int*)d_in[2];
    const int*   dego = (const int*)d_in[3];
    const float* posw = (const float*)d_in[4];
    const float* negw = (const float*)d_in[5];
    const float* bias = (const float*)d_in[6];
    float* out = (float*)d_out;
    float* ws  = (float*)d_ws;

    hipLaunchKernelGGL(phaseA, dim3(1), dim3(1024), 0, stream,
                       iu, io, posw, negw, bias, ws);

    hipLaunchKernelGGL(phaseBC, dim3(NB + NTAIL, 2), dim3(256), 0, stream,
                       ws, degu, dego, out);
}